// Round 8
// baseline (330.949 us; speedup 1.0000x reference)
//
#include <hip/hip_runtime.h>
#include <hip/hip_bf16.h>
#include <cstdint>

#define B_ROWS 4096
#define DIM 1024
#define NN 8192  // 2*B

typedef float f32x4 __attribute__((ext_vector_type(4)));
typedef int v4i __attribute__((ext_vector_type(4)));
typedef int v8i __attribute__((ext_vector_type(8)));

__device__ __forceinline__ float wave_reduce_sum(float v) {
    v += __shfl_xor(v, 1);
    v += __shfl_xor(v, 2);
    v += __shfl_xor(v, 4);
    v += __shfl_xor(v, 8);
    v += __shfl_xor(v, 16);
    v += __shfl_xor(v, 32);
    return v;
}

__device__ __forceinline__ void gld_lds16(const void* g, void* l) {
    __builtin_amdgcn_global_load_lds(
        (__attribute__((address_space(1))) void*)(uintptr_t)g,
        (__attribute__((address_space(3))) void*)l, 16, 0, 0);
}

// fp32 -> OCP e4m3fn, round-to-nearest-even. Inputs here satisfy |x| < 0.5,
// so no overflow/NaN handling needed. Subnormal cutoff at 2^-6.
__device__ __forceinline__ unsigned char f32_to_e4m3(float x) {
    unsigned int b = __float_as_uint(x);
    unsigned int sign = (b >> 24) & 0x80u;
    unsigned int ab = b & 0x7FFFFFFFu;
    unsigned int out;
    if (__uint_as_float(ab) >= 0.015625f) {
        unsigned int rb = ab + 0x7FFFFu + ((ab >> 20) & 1u);  // RNE at 3 mantissa bits
        int E = (int)(rb >> 23) - 127;
        out = (unsigned int)((E + 7) << 3) | ((rb >> 20) & 7u);
    } else {
        out = (unsigned int)rintf(__uint_as_float(ab) * 512.0f);  // subnormal, 0..8
    }
    return (unsigned char)(out | sign);
}

// Kernel 1: fused L2-normalize (both views) -> fp8 rep, + fp32 positives.
__global__ void norm_pos_kernel(const float* __restrict__ p1,
                                const float* __restrict__ p2,
                                unsigned char* __restrict__ rep,
                                float* __restrict__ pos) {
    const int i = blockIdx.x;   // 0..4095
    const int t = threadIdx.x;  // 0..255, one float4 each (DIM=1024)
    float4 a = ((const float4*)(p1 + (size_t)i * DIM))[t];
    float4 b = ((const float4*)(p2 + (size_t)i * DIM))[t];
    float s1 = a.x * a.x + a.y * a.y + a.z * a.z + a.w * a.w;
    float s2 = b.x * b.x + b.y * b.y + b.z * b.z + b.w * b.w;
    float dp = a.x * b.x + a.y * b.y + a.z * b.z + a.w * b.w;
    s1 = wave_reduce_sum(s1);
    s2 = wave_reduce_sum(s2);
    dp = wave_reduce_sum(dp);
    __shared__ float r1[4], r2[4], r3[4];
    const int lane = t & 63, wv = t >> 6;
    if (lane == 0) { r1[wv] = s1; r2[wv] = s2; r3[wv] = dp; }
    __syncthreads();
    const float t1 = r1[0] + r1[1] + r1[2] + r1[3];
    const float t2 = r2[0] + r2[1] + r2[2] + r2[3];
    const float td = r3[0] + r3[1] + r3[2] + r3[3];
    const float sc1 = rsqrtf(t1), sc2 = rsqrtf(t2);
    uchar4 o1, o2;
    o1.x = f32_to_e4m3(a.x * sc1); o1.y = f32_to_e4m3(a.y * sc1);
    o1.z = f32_to_e4m3(a.z * sc1); o1.w = f32_to_e4m3(a.w * sc1);
    o2.x = f32_to_e4m3(b.x * sc2); o2.y = f32_to_e4m3(b.y * sc2);
    o2.z = f32_to_e4m3(b.z * sc2); o2.w = f32_to_e4m3(b.w * sc2);
    *(uchar4*)(rep + (size_t)i * DIM + t * 4) = o1;
    *(uchar4*)(rep + (size_t)(i + B_ROWS) * DIM + t * 4) = o2;
    if (t == 0) pos[i] = td * sc1 * sc2;
}

// Kernel 2: symmetric fused GEMM, MX-scaled fp8 (unit scales), upper-triangle
// tiles (rb<=cb), BK=128, 2x2 waves (64x64 each, 4x4 frags of 16x16x128).
//
// LDS layout: 4 regions of 4 KB per operand, region(rh,kh) = rh*2+kh, each
// region = 64 rows x 64 k, row-major 64 B rows, 16 B segs XOR-swizzled by
// (row>>1)&3 (global_load_lds forces slot = t*16; staging picks the global
// seg (t&3)^((sr>>1)&3) so the reader's XOR undoes it -> every lane holds
// TRUE global k-segs). Lane (row, q) operand = seg q of kh=0 ++ seg q of
// kh=1: identical global k-set for A and B lanes => contraction consistent.
// 16 ds_read_b128 per wave per BK=128 (same bytes/K as R7), but MFMA count
// drops 4x at 2.27x the per-inst FLOP rate (MX path).
__global__ __launch_bounds__(256, 2) void gemm_kernel(const unsigned char* __restrict__ rep,
                                                      float* __restrict__ partial) {
    // rb-major triangle decode: start(rb) = 64*rb - rb*(rb-1)/2
    const int bid = blockIdx.x;
    int rb = (int)(64.5f - sqrtf(4160.25f - 2.0f * (float)bid));
    while (64 * (rb + 1) - (rb + 1) * rb / 2 <= bid) ++rb;
    while (64 * rb - rb * (rb - 1) / 2 > bid) --rb;
    const int cb = rb + (bid - (64 * rb - rb * (rb - 1) / 2));

    __shared__ __align__(16) unsigned char As[128 * 128];  // 16 KB, 4 regions
    __shared__ __align__(16) unsigned char Bs[128 * 128];  // 16 KB
    const int t = threadIdx.x;
    const int lane = t & 63;
    const int wv = t >> 6;     // 0..3
    const int wr = wv >> 1;    // wave row-half
    const int wc = wv & 1;     // wave col-half
    const int cm = lane & 15;  // frag m,n index
    const int q = lane >> 4;   // frag k-quarter

    // staging source: row sr = t>>2 within 64-row group, swizzled 16B seg
    const int sr = t >> 2;
    const int sg = (t & 3) ^ ((sr >> 1) & 3);
    const unsigned char* aS = rep + (size_t)(rb * 128 + sr) * DIM + sg * 16;
    const unsigned char* bS = rep + (size_t)(cb * 128 + sr) * DIM + sg * 16;
    unsigned char* aD = As + t * 16;  // HW-forced: wave-uniform base + lane*16
    unsigned char* bD = Bs + t * 16;

    // fragment read bases (k-invariant): region pair (half*2 + kh)
    const int fsw = (cm >> 1) & 3;
    const unsigned char* aF = As + wr * 8192 + cm * 64 + ((q ^ fsw) << 4);
    const unsigned char* bF = Bs + wc * 8192 + cm * 64 + ((q ^ fsw) << 4);

    f32x4 acc[4][4];
#pragma unroll
    for (int i = 0; i < 4; ++i)
#pragma unroll
        for (int j = 0; j < 4; ++j) acc[i][j] = (f32x4){0.f, 0.f, 0.f, 0.f};

    for (int kk = 0; kk < DIM / 128; ++kk) {
        const unsigned char* a0 = aS + kk * 128;
        const unsigned char* b0 = bS + kk * 128;
        gld_lds16(a0, aD);                                  // rh0 kh0 -> region 0
        gld_lds16(a0 + 64, aD + 4096);                      // rh0 kh1 -> region 1
        gld_lds16(a0 + (size_t)64 * DIM, aD + 8192);        // rh1 kh0 -> region 2
        gld_lds16(a0 + (size_t)64 * DIM + 64, aD + 12288);  // rh1 kh1 -> region 3
        gld_lds16(b0, bD);
        gld_lds16(b0 + 64, bD + 4096);
        gld_lds16(b0 + (size_t)64 * DIM, bD + 8192);
        gld_lds16(b0 + (size_t)64 * DIM + 64, bD + 12288);
        __syncthreads();

        v8i af[4], bf[4];
#pragma unroll
        for (int mi = 0; mi < 4; ++mi) {
            v4i lo = *(const v4i*)(aF + mi * 1024);
            v4i hi = *(const v4i*)(aF + mi * 1024 + 4096);
            af[mi] = __builtin_shufflevector(lo, hi, 0, 1, 2, 3, 4, 5, 6, 7);
        }
#pragma unroll
        for (int ni = 0; ni < 4; ++ni) {
            v4i lo = *(const v4i*)(bF + ni * 1024);
            v4i hi = *(const v4i*)(bF + ni * 1024 + 4096);
            bf[ni] = __builtin_shufflevector(lo, hi, 0, 1, 2, 3, 4, 5, 6, 7);
        }
#pragma unroll
        for (int mi = 0; mi < 4; ++mi)
#pragma unroll
            for (int ni = 0; ni < 4; ++ni)
                acc[mi][ni] = __builtin_amdgcn_mfma_scale_f32_16x16x128_f8f6f4(
                    af[mi], bf[ni], acc[mi][ni],
                    0, 0,                  // cbsz=0 (fp8 e4m3), blgp=0 (fp8 e4m3)
                    0, 0x7F7F7F7F,         // op_sel_a, scale_a = 2^0 (E8M0 127)
                    0, 0x7F7F7F7F);        // op_sel_b, scale_b = 2^0
        __syncthreads();
    }

    // Epilogue. C/D layout: col = wc*64 + ni*16 + cm, row = wr*64 + mi*16 + q*4 + reg.
    // Row-partials -> slot 2*cb+wc; transpose col-partials -> slot 2*rb+wr.
    // Row r of block i receives slots {2c,2c+1 : c>=i} ∪ {2c,2c+1 : c<i} = all 128, disjoint.
    float colsum[4];
#pragma unroll
    for (int ni = 0; ni < 4; ++ni) colsum[ni] = 0.f;

#pragma unroll
    for (int mi = 0; mi < 4; ++mi) {
#pragma unroll
        for (int reg = 0; reg < 4; ++reg) {
            const int grow = rb * 128 + wr * 64 + mi * 16 + (q << 2) + reg;
            float rs = 0.f;
#pragma unroll
            for (int ni = 0; ni < 4; ++ni) {
                const int gcol = cb * 128 + wc * 64 + ni * 16 + cm;
                const float e =
                    (grow == gcol) ? 0.f : __expf(acc[mi][ni][reg] * 2.0f);  // 1/T=2
                rs += e;
                colsum[ni] += e;
            }
            rs += __shfl_xor(rs, 1);
            rs += __shfl_xor(rs, 2);
            rs += __shfl_xor(rs, 4);
            rs += __shfl_xor(rs, 8);
            if (cm == 0) partial[(size_t)(2 * cb + wc) * NN + grow] = rs;
        }
    }

    if (rb != cb) {
#pragma unroll
        for (int ni = 0; ni < 4; ++ni) {
            colsum[ni] += __shfl_xor(colsum[ni], 16);  // fold q
            colsum[ni] += __shfl_xor(colsum[ni], 32);
        }
        if (q == 0) {
#pragma unroll
            for (int ni = 0; ni < 4; ++ni)
                partial[(size_t)(2 * rb + wr) * NN + cb * 128 + wc * 64 + ni * 16 + cm] =
                    colsum[ni];
        }
    }
}

// Kernel 3: per-row denom (128 slots) -> per-row loss -> atomic into out[0].
__global__ void reduce_rows_kernel(const float* __restrict__ partial,
                                   const float* __restrict__ pos,
                                   float* __restrict__ out) {
    const int r = blockIdx.x * 256 + threadIdx.x;  // 32 x 256 = 8192
    float s0 = 0.f, s1 = 0.f, s2 = 0.f, s3 = 0.f;
    for (int kb = 0; kb < 128; kb += 4) {
        s0 += partial[(size_t)(kb + 0) * NN + r];
        s1 += partial[(size_t)(kb + 1) * NN + r];
        s2 += partial[(size_t)(kb + 2) * NN + r];
        s3 += partial[(size_t)(kb + 3) * NN + r];
    }
    const float s = (s0 + s1) + (s2 + s3);
    float v = __logf(s) - pos[r & (B_ROWS - 1)] * 2.0f;  // log(denom) - pos/T
    v = wave_reduce_sum(v);
    __shared__ float red[4];
    const int lane = threadIdx.x & 63, wv = threadIdx.x >> 6;
    if (lane == 0) red[wv] = v;
    __syncthreads();
    if (threadIdx.x == 0)
        atomicAdd(out, (red[0] + red[1] + red[2] + red[3]) * (1.0f / NN));
}

extern "C" void kernel_launch(void* const* d_in, const int* in_sizes, int n_in,
                              void* d_out, int out_size, void* d_ws, size_t ws_size,
                              hipStream_t stream) {
    const float* p1 = (const float*)d_in[0];
    const float* p2 = (const float*)d_in[1];
    char* ws = (char*)d_ws;
    unsigned char* rep = (unsigned char*)ws;                  // 8 MiB (fp8)
    float* partial = (float*)(ws + (size_t)8 * 1024 * 1024);  // 4 MiB (128 x 8192)
    float* pos = (float*)(ws + (size_t)12 * 1024 * 1024);     // 16 KiB
    float* out = (float*)d_out;

    hipMemsetAsync(out, 0, sizeof(float), stream);
    norm_pos_kernel<<<B_ROWS, 256, 0, stream>>>(p1, p2, rep, pos);
    gemm_kernel<<<2080, 256, 0, stream>>>(rep, partial);
    reduce_rows_kernel<<<32, 256, 0, stream>>>(partial, pos, out);
}

// Round 9
// 151.381 us; speedup vs baseline: 2.1862x; 2.1862x over previous
//
#include <hip/hip_runtime.h>
#include <hip/hip_bf16.h>
#include <cstdint>

#define B_ROWS 4096
#define DIM 1024
#define NN 8192  // 2*B

typedef float f32x4 __attribute__((ext_vector_type(4)));
typedef long lx2 __attribute__((ext_vector_type(2)));

__device__ __forceinline__ float wave_reduce_sum(float v) {
    v += __shfl_xor(v, 1);
    v += __shfl_xor(v, 2);
    v += __shfl_xor(v, 4);
    v += __shfl_xor(v, 8);
    v += __shfl_xor(v, 16);
    v += __shfl_xor(v, 32);
    return v;
}

__device__ __forceinline__ void gld_lds16(const void* g, void* l) {
    __builtin_amdgcn_global_load_lds(
        (__attribute__((address_space(1))) void*)(uintptr_t)g,
        (__attribute__((address_space(3))) void*)l, 16, 0, 0);
}

// fp32 -> OCP e4m3fn, round-to-nearest-even. Inputs here satisfy |x| < 0.5,
// so no overflow/NaN handling needed. Subnormal cutoff at 2^-6.
__device__ __forceinline__ unsigned char f32_to_e4m3(float x) {
    unsigned int b = __float_as_uint(x);
    unsigned int sign = (b >> 24) & 0x80u;
    unsigned int ab = b & 0x7FFFFFFFu;
    unsigned int out;
    if (__uint_as_float(ab) >= 0.015625f) {
        unsigned int rb = ab + 0x7FFFFu + ((ab >> 20) & 1u);  // RNE at 3 mantissa bits
        int E = (int)(rb >> 23) - 127;
        out = (unsigned int)((E + 7) << 3) | ((rb >> 20) & 7u);
    } else {
        out = (unsigned int)rintf(__uint_as_float(ab) * 512.0f);  // subnormal, 0..8
    }
    return (unsigned char)(out | sign);
}

// Kernel 1: fused L2-normalize (both views) -> fp8 rep, + fp32 positives.
__global__ void norm_pos_kernel(const float* __restrict__ p1,
                                const float* __restrict__ p2,
                                unsigned char* __restrict__ rep,
                                float* __restrict__ pos) {
    const int i = blockIdx.x;   // 0..4095
    const int t = threadIdx.x;  // 0..255, one float4 each (DIM=1024)
    float4 a = ((const float4*)(p1 + (size_t)i * DIM))[t];
    float4 b = ((const float4*)(p2 + (size_t)i * DIM))[t];
    float s1 = a.x * a.x + a.y * a.y + a.z * a.z + a.w * a.w;
    float s2 = b.x * b.x + b.y * b.y + b.z * b.z + b.w * b.w;
    float dp = a.x * b.x + a.y * b.y + a.z * b.z + a.w * b.w;
    s1 = wave_reduce_sum(s1);
    s2 = wave_reduce_sum(s2);
    dp = wave_reduce_sum(dp);
    __shared__ float r1[4], r2[4], r3[4];
    const int lane = t & 63, wv = t >> 6;
    if (lane == 0) { r1[wv] = s1; r2[wv] = s2; r3[wv] = dp; }
    __syncthreads();
    const float t1 = r1[0] + r1[1] + r1[2] + r1[3];
    const float t2 = r2[0] + r2[1] + r2[2] + r2[3];
    const float td = r3[0] + r3[1] + r3[2] + r3[3];
    const float sc1 = rsqrtf(t1), sc2 = rsqrtf(t2);
    uchar4 o1, o2;
    o1.x = f32_to_e4m3(a.x * sc1); o1.y = f32_to_e4m3(a.y * sc1);
    o1.z = f32_to_e4m3(a.z * sc1); o1.w = f32_to_e4m3(a.w * sc1);
    o2.x = f32_to_e4m3(b.x * sc2); o2.y = f32_to_e4m3(b.y * sc2);
    o2.z = f32_to_e4m3(b.z * sc2); o2.w = f32_to_e4m3(b.w * sc2);
    *(uchar4*)(rep + (size_t)i * DIM + t * 4) = o1;
    *(uchar4*)(rep + (size_t)(i + B_ROWS) * DIM + t * 4) = o2;
    if (t == 0) pos[i] = td * sc1 * sc2;
}

// Kernel 2: symmetric fused GEMM in fp8 e4m3 (non-scaled — R8's MX-scaled
// builtin spilled to scratch: VGPR 128, WRITE_SIZE 489 MB, 5x regression).
// Upper-triangle tiles (rb<=cb), BK=64, 2x2 waves (64x64 each, 4x4 frags).
//
// DOUBLE-BUFFERED LDS, one barrier per iter: at top of iter k the barrier
// guarantees (a) tile k's gld_lds (issued iter k-1) drained — the issuing
// wave's vmcnt(0) precedes its barrier — and (b) all reads of the other
// buffer's old tile finished. Then tile k+1 is issued into buf^1 and has
// the entire MFMA block (~600 cyc) to land: global latency hidden, barrier
// count halved vs R7.
//
// K-permutation trick (R7): within BK=64 any k-bijection applied to both
// operands is contraction-invariant, so each lane ds_read_b128's its
// swizzled 16 B slot once; low 8 B -> MFMA 0, high 8 B -> MFMA 1.
// Staging: thread t -> row t>>2, global 16B seg (t&3)^((row>>1)&3):
// per-quad one 64 B run (coalesced); LDS slot forced to t*16.
__global__ __launch_bounds__(256) void gemm_kernel(const unsigned char* __restrict__ rep,
                                                   float* __restrict__ partial) {
    // rb-major triangle decode: start(rb) = 64*rb - rb*(rb-1)/2
    const int bid = blockIdx.x;
    int rb = (int)(64.5f - sqrtf(4160.25f - 2.0f * (float)bid));
    while (64 * (rb + 1) - (rb + 1) * rb / 2 <= bid) ++rb;
    while (64 * rb - rb * (rb - 1) / 2 > bid) --rb;
    const int cb = rb + (bid - (64 * rb - rb * (rb - 1) / 2));

    __shared__ __align__(16) unsigned char As[2 * 8192];  // 16 KB (2 buffers)
    __shared__ __align__(16) unsigned char Bs[2 * 8192];  // 16 KB
    const int t = threadIdx.x;
    const int lane = t & 63;
    const int wv = t >> 6;     // 0..3
    const int wr = wv >> 1;    // wave row-half
    const int wc = wv & 1;     // wave col-half
    const int cm = lane & 15;  // frag m,n index
    const int q = lane >> 4;   // frag k-quarter

    // staging source
    const int sr = t >> 2;
    const int sg = (t & 3) ^ ((sr >> 1) & 3);
    const unsigned char* aS = rep + (size_t)(rb * 128 + sr) * DIM + sg * 16;
    const unsigned char* bS = rep + (size_t)(cb * 128 + sr) * DIM + sg * 16;
    unsigned char* aD = As + t * 16;  // HW-forced: wave-uniform base + lane*16
    unsigned char* bD = Bs + t * 16;

    // fragment read bases (k-invariant): row cm within 64-row group, slot q^fsw
    const int fsw = (cm >> 1) & 3;
    const unsigned char* aF = As + wr * 4096 + cm * 64 + ((q ^ fsw) << 4);
    const unsigned char* bF = Bs + wc * 4096 + cm * 64 + ((q ^ fsw) << 4);

    f32x4 acc[4][4];
#pragma unroll
    for (int i = 0; i < 4; ++i)
#pragma unroll
        for (int j = 0; j < 4; ++j) acc[i][j] = (f32x4){0.f, 0.f, 0.f, 0.f};

    // prologue: tile 0 -> buffer 0
    gld_lds16(aS, aD);
    gld_lds16(aS + (size_t)64 * DIM, aD + 4096);
    gld_lds16(bS, bD);
    gld_lds16(bS + (size_t)64 * DIM, bD + 4096);

    for (int kk = 0; kk < DIM / 64; ++kk) {
        const int cur = (kk & 1) * 8192;
        __syncthreads();  // tile kk ready in buf[cur]; buf[nxt] free
        if (kk + 1 < DIM / 64) {
            const int nxt = 8192 - cur;
            const unsigned char* a0 = aS + (kk + 1) * 64;
            const unsigned char* b0 = bS + (kk + 1) * 64;
            gld_lds16(a0, aD + nxt);
            gld_lds16(a0 + (size_t)64 * DIM, aD + nxt + 4096);
            gld_lds16(b0, bD + nxt);
            gld_lds16(b0 + (size_t)64 * DIM, bD + nxt + 4096);
        }

        lx2 af[4], bf[4];
#pragma unroll
        for (int mi = 0; mi < 4; ++mi) af[mi] = *(const lx2*)(aF + cur + mi * 1024);
#pragma unroll
        for (int ni = 0; ni < 4; ++ni) bf[ni] = *(const lx2*)(bF + cur + ni * 1024);
#pragma unroll
        for (int h = 0; h < 2; ++h)
#pragma unroll
            for (int mi = 0; mi < 4; ++mi)
#pragma unroll
                for (int ni = 0; ni < 4; ++ni)
                    acc[mi][ni] = __builtin_amdgcn_mfma_f32_16x16x32_fp8_fp8(
                        af[mi][h], bf[ni][h], acc[mi][ni], 0, 0, 0);
    }

    // Epilogue. C/D layout: col = wc*64 + ni*16 + cm, row = wr*64 + mi*16 + q*4 + reg.
    // Row-partials -> slot 2*cb+wc; transpose col-partials -> slot 2*rb+wr.
    // Row r of block i receives slots {2c,2c+1 : c>=i} ∪ {2c,2c+1 : c<i} = all 128, disjoint.
    float colsum[4];
#pragma unroll
    for (int ni = 0; ni < 4; ++ni) colsum[ni] = 0.f;

#pragma unroll
    for (int mi = 0; mi < 4; ++mi) {
#pragma unroll
        for (int reg = 0; reg < 4; ++reg) {
            const int grow = rb * 128 + wr * 64 + mi * 16 + (q << 2) + reg;
            float rs = 0.f;
#pragma unroll
            for (int ni = 0; ni < 4; ++ni) {
                const int gcol = cb * 128 + wc * 64 + ni * 16 + cm;
                const float e =
                    (grow == gcol) ? 0.f : __expf(acc[mi][ni][reg] * 2.0f);  // 1/T=2
                rs += e;
                colsum[ni] += e;
            }
            rs += __shfl_xor(rs, 1);
            rs += __shfl_xor(rs, 2);
            rs += __shfl_xor(rs, 4);
            rs += __shfl_xor(rs, 8);
            if (cm == 0) partial[(size_t)(2 * cb + wc) * NN + grow] = rs;
        }
    }

    if (rb != cb) {
#pragma unroll
        for (int ni = 0; ni < 4; ++ni) {
            colsum[ni] += __shfl_xor(colsum[ni], 16);  // fold q
            colsum[ni] += __shfl_xor(colsum[ni], 32);
        }
        if (q == 0) {
#pragma unroll
            for (int ni = 0; ni < 4; ++ni)
                partial[(size_t)(2 * rb + wr) * NN + cb * 128 + wc * 64 + ni * 16 + cm] =
                    colsum[ni];
        }
    }
}

// Kernel 3: per-row denom (128 slots) -> per-row loss -> atomic into out[0].
__global__ void reduce_rows_kernel(const float* __restrict__ partial,
                                   const float* __restrict__ pos,
                                   float* __restrict__ out) {
    const int r = blockIdx.x * 256 + threadIdx.x;  // 32 x 256 = 8192
    float s0 = 0.f, s1 = 0.f, s2 = 0.f, s3 = 0.f;
    for (int kb = 0; kb < 128; kb += 4) {
        s0 += partial[(size_t)(kb + 0) * NN + r];
        s1 += partial[(size_t)(kb + 1) * NN + r];
        s2 += partial[(size_t)(kb + 2) * NN + r];
        s3 += partial[(size_t)(kb + 3) * NN + r];
    }
    const float s = (s0 + s1) + (s2 + s3);
    float v = __logf(s) - pos[r & (B_ROWS - 1)] * 2.0f;  // log(denom) - pos/T
    v = wave_reduce_sum(v);
    __shared__ float red[4];
    const int lane = threadIdx.x & 63, wv = threadIdx.x >> 6;
    if (lane == 0) red[wv] = v;
    __syncthreads();
    if (threadIdx.x == 0)
        atomicAdd(out, (red[0] + red[1] + red[2] + red[3]) * (1.0f / NN));
}

extern "C" void kernel_launch(void* const* d_in, const int* in_sizes, int n_in,
                              void* d_out, int out_size, void* d_ws, size_t ws_size,
                              hipStream_t stream) {
    const float* p1 = (const float*)d_in[0];
    const float* p2 = (const float*)d_in[1];
    char* ws = (char*)d_ws;
    unsigned char* rep = (unsigned char*)ws;                  // 8 MiB (fp8)
    float* partial = (float*)(ws + (size_t)8 * 1024 * 1024);  // 4 MiB (128 x 8192)
    float* pos = (float*)(ws + (size_t)12 * 1024 * 1024);     // 16 KiB
    float* out = (float*)d_out;

    hipMemsetAsync(out, 0, sizeof(float), stream);
    norm_pos_kernel<<<B_ROWS, 256, 0, stream>>>(p1, p2, rep, pos);
    gemm_kernel<<<2080, 256, 0, stream>>>(rep, partial);
    reduce_rows_kernel<<<32, 256, 0, stream>>>(partial, pos, out);
}